// Round 1
// baseline (258.731 us; speedup 1.0000x reference)
//
#include <hip/hip_runtime.h>
#include <math.h>

// Problem constants (from reference setup_inputs): B=16, A=16384, C=81, TOP_K=64
constexpr int B_N  = 16;
constexpr int A_N  = 16384;
constexpr int C_N  = 81;
constexpr int TOPK = 64;
constexpr int DNT  = 256;            // decode kernel block size
constexpr int NBINS = 232;           // score-bit bins covering (0.3, 1.0)
constexpr int CAP   = 512;           // candidate band capacity (pow2, 8/lane)
constexpr unsigned BIN_BASE = 0x3E99u;   // __float_as_uint(0.3f) >> 16

// sigmoid+transpose tile: 64 anchors x 81 classes per block, LINEAR layout.
// Phase 1: float4 loads + ds_write_b128 (dense 16B/lane = conflict-free).
// Phase 2: 4x ds_read_b32 at dword addr (al4*4+k)*81+cc -> bank 4*al4+g
// pattern = exactly 2 lanes/bank (free, m136). 20.7 KB LDS -> 7 blocks/CU.
constexpr int TA   = 64;
constexpr int TNT  = 256;
constexpr int TILE_ELEMS = TA * C_N;       // 5184
constexpr int TILE_F4    = TILE_ELEMS / 4; // 1296

// ---------------------------------------------------------------------------
// Kernel 1: SSD box decode (unchanged — bit-exact vs ref across all rounds).
// ---------------------------------------------------------------------------
__global__ __launch_bounds__(DNT) void decode_kernel(const float4* __restrict__ loc,
                                                     const float4* __restrict__ anch,
                                                     float4* __restrict__ boxes) {
    int i = blockIdx.x * DNT + threadIdx.x;
    int a = i & (A_N - 1);
    float4 l  = loc[i];
    float4 an = anch[a];
    float cx = an.x + (l.x * 0.1f) * an.z;
    float cy = an.y + (l.y * 0.1f) * an.w;
    float w  = an.z * expf(l.z * 0.2f);
    float h  = an.w * expf(l.w * 0.2f);
    float x1 = cx - w * 0.5f;
    float y1 = cy - h * 0.5f;
    boxes[i] = make_float4(x1, y1, x1 + w, y1 + h);
}

// ---------------------------------------------------------------------------
// Kernel 1b: fused sigmoid + transpose, v4 (vectorized loads, linear LDS).
// Sigmoid expression identical to all passing rounds; stored fp32 values
// bit-identical (same per-element expression, just 4 at a time).
// ---------------------------------------------------------------------------
__global__ __launch_bounds__(TNT) void sigT_kernel(const float* __restrict__ conf,
                                                   float* __restrict__ scoresT) {
    __shared__ float4 tile4[TILE_F4];          // 20.7 KB, linear (mirrors global)
    float* tile = (float*)tile4;

    const int a0 = blockIdx.x * TA;
    const int b  = blockIdx.y;
    const int t  = threadIdx.x;

    const float4* src = (const float4*)(conf + ((size_t)b * A_N + a0) * C_N);
#pragma unroll
    for (int i = 0; i < (TILE_F4 + TNT - 1) / TNT; ++i) {   // 6 iters (last partial)
        int idx4 = i * TNT + t;
        if (idx4 < TILE_F4) {
            float4 x = src[idx4];                            // dwordx4, coalesced
            float4 v;
            v.x = 1.0f / (1.0f + expf(-x.x));
            v.y = 1.0f / (1.0f + expf(-x.y));
            v.z = 1.0f / (1.0f + expf(-x.z));
            v.w = 1.0f / (1.0f + expf(-x.w));
            tile4[idx4] = v;                                 // ds_write_b128, dense
        }
    }
    __syncthreads();
    float* dst = scoresT + (size_t)b * C_N * A_N + a0;
#pragma unroll
    for (int i = 0; i < (TILE_F4 + TNT - 1) / TNT; ++i) {
        int idx4 = i * TNT + t;
        if (idx4 < TILE_F4) {
            int cc  = idx4 >> 4;                   // 16 float4 per class row
            int al4 = idx4 & 15;
            int e   = al4 * 4 * C_N + cc;
            float4 v;
            v.x = tile[e];
            v.y = tile[e + C_N];
            v.z = tile[e + 2 * C_N];
            v.w = tile[e + 3 * C_N];
            ((float4*)(dst + (size_t)cc * A_N))[al4] = v;   // dwordx4 stores
        }
    }
}

// ---------------------------------------------------------------------------
// Shared device routine: wave-level bitonic sort of <=CAP keys + box gather +
// ordered greedy NMS scan. Verbatim semantics from the passing rounds
// (key = (score_bits<<32)|~idx => unique keys => order independent of
// compaction arrival order; same IoU operand order; same accept logic).
// ---------------------------------------------------------------------------
__device__ __forceinline__ void sort_gather_scan64(
        unsigned long long* cand, float4* cbox, int C, int lane,
        const float4* __restrict__ bptr, float* __restrict__ optr,
        float& rx1, float& ry1, float& rx2, float& ry2, float& rar,
        int& acc, int& kout) {
    unsigned long long key[8];
#pragma unroll
    for (int r = 0; r < 8; ++r) {
        int sidx = r * 64 + lane;
        key[r] = (sidx < C) ? cand[sidx] : 0ull;   // pad: 0 < any real key
    }
#pragma unroll
    for (int k = 2; k <= CAP; k <<= 1) {
#pragma unroll
        for (int j = k >> 1; j > 0; j >>= 1) {
            if (j >= 64) {
                int jr = j >> 6;               // 1,2,4: in-lane pairs
#pragma unroll
                for (int r = 0; r < 8; ++r) {
                    int rp = r ^ jr;
                    if (rp > r) {
                        int e = r * 64 + lane;
                        bool up = ((e & k) == 0);
                        unsigned long long va = key[r], vb = key[rp];
                        bool sw = up ? (va < vb) : (va > vb);
                        if (sw) { key[r] = vb; key[rp] = va; }
                    }
                }
            } else {                            // cross-lane via shfl
#pragma unroll
                for (int r = 0; r < 8; ++r) {
                    int e = r * 64 + lane;
                    bool up    = ((e & k) == 0);
                    bool isLow = ((lane & j) == 0);
                    unsigned long long va = key[r];
                    unsigned long long vb = __shfl_xor(va, j, 64);
                    bool keepMax = (up == isLow);
                    key[r] = keepMax ? (va > vb ? va : vb) : (va < vb ? va : vb);
                }
            }
        }
    }
    __syncthreads();
#pragma unroll
    for (int r = 0; r < 8; ++r) cand[r * 64 + lane] = key[r];
    __syncthreads();
#pragma unroll
    for (int r = 0; r < 8; ++r) {
        int e = r * 64 + lane;
        if (e < C) cbox[e] = bptr[(int)(~(unsigned)cand[e])];
    }
    __syncthreads();

    int ts = 0;
    unsigned long long k0 = cand[0];
    float4 cb = cbox[0];
    while (ts < C) {
        unsigned long long nk = 0ull;
        float4 nb = cb;
        if (ts + 1 < C) { nk = cand[ts + 1]; nb = cbox[ts + 1]; }
        float sc = __uint_as_float((unsigned)(k0 >> 32));
        float ca = (cb.z - cb.x) * (cb.w - cb.y);
        bool over = false;
        if (lane < acc) {
            float tlx = fmaxf(rx1, cb.x);
            float tly = fmaxf(ry1, cb.y);
            float brx = fminf(rx2, cb.z);
            float bry = fminf(ry2, cb.w);
            float iw  = fmaxf(brx - tlx, 0.0f);
            float ih  = fmaxf(bry - tly, 0.0f);
            float inter = iw * ih;
            float iou = inter / (rar + ca - inter);   // ref operand order
            over = iou > 0.5f;
        }
        if (!__any(over)) {
            if (lane == acc) { rx1 = cb.x; ry1 = cb.y; rx2 = cb.z; ry2 = cb.w; rar = ca; }
            if (lane == 0) {
                float* o = optr + (size_t)kout * 5;
                o[0] = sc; o[1] = cb.x; o[2] = cb.y; o[3] = cb.z; o[4] = cb.w;
            }
            acc++; kout++;
            if (acc == TOPK) break;
        }
        ++ts; k0 = nk; cb = nb;
    }
}

// ---------------------------------------------------------------------------
// Kernel 2: fused select + NMS, v2 — ONE 64-THREAD WAVE per (b,c).
// Rationale (rocprof): the 256-thread version idled 3/4 waves during the
// wave-0 sort+scan (VALUBusy 36%) and needed a second scheduling round
// (1296 blocks > 1024 resident). 1296 one-wave blocks at 13.3 KB LDS are
// ALL resident simultaneously (5 waves/CU << 12-block LDS cap): no barrier
// idling, no tail. Same bins / band walk / keys / sort / scan semantics
// => identical candidate selection (keys unique, order arrival-invariant).
// ---------------------------------------------------------------------------
__global__ __launch_bounds__(64, 4) void select_nms_kernel(
        const float* __restrict__ scoresT,
        const float4* __restrict__ boxes,
        float* __restrict__ out) {
    __shared__ int hist[NBINS];
    __shared__ unsigned long long cand[CAP];
    __shared__ float4 cbox[CAP];
    __shared__ int s_cnt;

    const int bc   = blockIdx.x;           // b*C_N + c
    const int b    = bc / C_N;
    const int lane = threadIdx.x;

    for (int i = lane; i < NBINS; i += 64) hist[i] = 0;
    __syncthreads();

    const float4* sptr = (const float4*)(scoresT + (size_t)bc * A_N);
    const float4* bptr = boxes + (size_t)b * A_N;
    float* optr = out + (size_t)bc * TOPK * 5;

    // --- pass 1: histogram (coalesced float4 reads, unroll-8 for MLP) ---
#pragma unroll 8
    for (int i = 0; i < A_N / 4 / 64; ++i) {       // 64 iterations
        float4 s4 = sptr[lane + 64 * i];
        float s[4] = {s4.x, s4.y, s4.z, s4.w};
#pragma unroll
        for (int q = 0; q < 4; ++q) {
            if (s[q] > 0.3f) {
                unsigned u = __float_as_uint(s[q]);
                int bin = (int)(u >> 16) - (int)BIN_BASE;
                bin = bin < 0 ? 0 : (bin > NBINS - 1 ? NBINS - 1 : bin);
                atomicAdd(&hist[bin], 1);
            }
        }
    }
    __syncthreads();

    float rx1 = 0.f, ry1 = 0.f, rx2 = 0.f, ry2 = 0.f, rar = 0.f;
    int acc = 0, kout = 0;

    int bin_hi = NBINS;
    for (;;) {
        // --- band walk (redundant on all lanes; wave-uniform LDS reads) ---
        int lo = bin_hi, tot = 0;
        while (lo > 0) {
            int cnt = hist[lo - 1];
            if (tot + cnt > CAP) {
                if (tot == 0) { lo--; }            // single bin > CAP: take it (clamped)
                break;
            }
            tot += cnt; lo--;
        }
        const int bin_lo = lo;
        if (bin_lo == bin_hi) break;               // all bins consumed -> exhausted
        if (lane == 0) s_cnt = 0;
        __syncthreads();

        // --- pass 2: compact this band into LDS (L2/L3-warm reads) ---
#pragma unroll 8
        for (int i = 0; i < A_N / 4 / 64; ++i) {
            float4 s4 = sptr[lane + 64 * i];
            float s[4] = {s4.x, s4.y, s4.z, s4.w};
#pragma unroll
            for (int q = 0; q < 4; ++q) {
                if (s[q] > 0.3f) {
                    unsigned u = __float_as_uint(s[q]);
                    int bin = (int)(u >> 16) - (int)BIN_BASE;
                    bin = bin < 0 ? 0 : (bin > NBINS - 1 ? NBINS - 1 : bin);
                    if (bin >= bin_lo && bin < bin_hi) {
                        int slot = atomicAdd(&s_cnt, 1);
                        if (slot < CAP) {
                            unsigned a = (unsigned)(4 * (lane + 64 * i) + q);
                            cand[slot] = ((unsigned long long)u << 32) | (unsigned)(~a);
                        }
                    }
                }
            }
        }
        __syncthreads();
        int C = s_cnt; if (C > CAP) C = CAP;       // uniform across wave

        if (C > 0)
            sort_gather_scan64(cand, cbox, C, lane, bptr, optr,
                               rx1, ry1, rx2, ry2, rar, acc, kout);
        if (acc == TOPK) break;
        bin_hi = bin_lo;
    }

    // Zero-fill remaining rows (harness poisons d_out with 0xAA every launch).
    {
        float* o  = optr + (size_t)kout * 5;
        int   rem = (TOPK - kout) * 5;
        for (int i = lane; i < rem; i += 64) o[i] = 0.0f;
    }
}

// ---------------------------------------------------------------------------
// Fallback: standalone one-wave NMS reading strided conf (proven r6-8 path),
// used only if d_ws is too small for scoresT.
// ---------------------------------------------------------------------------
__global__ __launch_bounds__(64, 4) void nms_fallback(const float* __restrict__ conf,
                                                      const float4* __restrict__ boxes,
                                                      float* __restrict__ out) {
    __shared__ int hist[NBINS];
    __shared__ unsigned long long cand[CAP];
    __shared__ float4 cbox[CAP];
    __shared__ int s_cnt;

    const int c    = blockIdx.x;
    const int b    = blockIdx.y;
    const int lane = threadIdx.x;

    const float4* bptr = boxes + (size_t)b * A_N;
    const float*  cptr = conf + (size_t)b * A_N * C_N + c;
    float* optr = out + (size_t)(b * C_N + c) * TOPK * 5;

    for (int i = lane; i < NBINS; i += 64) hist[i] = 0;
    __syncthreads();
    for (int i = 0; i < A_N / 256; ++i) {
        int a0 = 4 * (lane + 64 * i);
#pragma unroll
        for (int q = 0; q < 4; ++q) {
            float x = cptr[(size_t)(a0 + q) * C_N];
            float s = 1.0f / (1.0f + expf(-x));
            if (s > 0.3f) {
                unsigned u = __float_as_uint(s);
                int bin = (int)(u >> 16) - (int)BIN_BASE;
                bin = bin < 0 ? 0 : (bin > NBINS - 1 ? NBINS - 1 : bin);
                atomicAdd(&hist[bin], 1);
            }
        }
    }
    __syncthreads();

    float rx1 = 0.f, ry1 = 0.f, rx2 = 0.f, ry2 = 0.f, rar = 0.f;
    int acc = 0, kout = 0;
    int bin_hi = NBINS;
    for (;;) {
        int lo = bin_hi, tot = 0;
        while (lo > 0) {
            int cnt = hist[lo - 1];
            if (tot + cnt > CAP) { if (tot == 0) { lo--; } break; }
            tot += cnt; lo--;
        }
        const int bin_lo = lo;
        if (bin_lo == bin_hi) break;
        if (lane == 0) s_cnt = 0;
        __syncthreads();
        for (int i = 0; i < A_N / 256; ++i) {
            int a0 = 4 * (lane + 64 * i);
#pragma unroll
            for (int q = 0; q < 4; ++q) {
                float x = cptr[(size_t)(a0 + q) * C_N];
                float s = 1.0f / (1.0f + expf(-x));
                if (s > 0.3f) {
                    unsigned u = __float_as_uint(s);
                    int bin = (int)(u >> 16) - (int)BIN_BASE;
                    bin = bin < 0 ? 0 : (bin > NBINS - 1 ? NBINS - 1 : bin);
                    if (bin >= bin_lo && bin < bin_hi) {
                        int slot = atomicAdd(&s_cnt, 1);
                        if (slot < CAP)
                            cand[slot] = ((unsigned long long)u << 32) | (unsigned)(~(unsigned)(a0 + q));
                    }
                }
            }
        }
        __syncthreads();
        int C = s_cnt; if (C > CAP) C = CAP;
        if (C > 0)
            sort_gather_scan64(cand, cbox, C, lane, bptr, optr,
                               rx1, ry1, rx2, ry2, rar, acc, kout);
        if (acc == TOPK) break;
        bin_hi = bin_lo;
    }
    {
        float* o  = optr + (size_t)kout * 5;
        int   rem = (TOPK - kout) * 5;
        for (int i = lane; i < rem; i += 64) o[i] = 0.0f;
    }
}

extern "C" void kernel_launch(void* const* d_in, const int* in_sizes, int n_in,
                              void* d_out, int out_size, void* d_ws, size_t ws_size,
                              hipStream_t stream) {
    const float* loc     = (const float*)d_in[0];   // [B, A, 4]
    const float* conf    = (const float*)d_in[1];   // [B, A, C]
    const float* anchors = (const float*)d_in[2];   // [A, 4]
    float* out = (float*)d_out;                     // [B, C, TOPK, 5]

    const size_t boxes_bytes  = (size_t)B_N * A_N * sizeof(float4);          // 4 MB
    const size_t scores_bytes = (size_t)B_N * C_N * A_N * sizeof(float);     // 85 MB

    float4* boxes = (float4*)d_ws;

    decode_kernel<<<(B_N * A_N) / DNT, DNT, 0, stream>>>(
        (const float4*)loc, (const float4*)anchors, boxes);

    if (ws_size >= boxes_bytes + scores_bytes) {
        float* scoresT = (float*)((char*)d_ws + boxes_bytes);
        sigT_kernel<<<dim3(A_N / TA, B_N), TNT, 0, stream>>>(conf, scoresT);
        select_nms_kernel<<<dim3(B_N * C_N), 64, 0, stream>>>(scoresT, boxes, out);
    } else {
        // fallback: strided conf reads, in-wave histogram (proven semantics)
        nms_fallback<<<dim3(C_N, B_N), 64, 0, stream>>>(conf, boxes, out);
    }
}

// Round 2
// 221.741 us; speedup vs baseline: 1.1668x; 1.1668x over previous
//
#include <hip/hip_runtime.h>
#include <math.h>

// Problem constants (from reference setup_inputs): B=16, A=16384, C=81, TOP_K=64
constexpr int B_N  = 16;
constexpr int A_N  = 16384;
constexpr int C_N  = 81;
constexpr int TOPK = 64;
constexpr int DNT  = 256;            // decode kernel block size
constexpr int NBINS = 232;           // score-bit bins covering (0.3, 1.0)
constexpr int CAP   = 512;           // candidate band capacity (pow2, 8/lane)
constexpr unsigned BIN_BASE = 0x3E99u;   // __float_as_uint(0.3f) >> 16
constexpr int SNT = 256;             // streaming select block size
constexpr int BC_N = B_N * C_N;      // 1296

// sigmoid+transpose tile: 64 anchors x 81 classes, linear LDS (round-1 v4,
// passed; time identical to v3 -> BW-plateaued, leave alone).
constexpr int TA   = 64;
constexpr int TNT  = 256;
constexpr int TILE_ELEMS = TA * C_N;       // 5184
constexpr int TILE_F4    = TILE_ELEMS / 4; // 1296

// ---------------------------------------------------------------------------
// Kernel 1: SSD box decode (unchanged — bit-exact vs ref across all rounds).
// ---------------------------------------------------------------------------
__global__ __launch_bounds__(DNT) void decode_kernel(const float4* __restrict__ loc,
                                                     const float4* __restrict__ anch,
                                                     float4* __restrict__ boxes) {
    int i = blockIdx.x * DNT + threadIdx.x;
    int a = i & (A_N - 1);
    float4 l  = loc[i];
    float4 an = anch[a];
    float cx = an.x + (l.x * 0.1f) * an.z;
    float cy = an.y + (l.y * 0.1f) * an.w;
    float w  = an.z * expf(l.z * 0.2f);
    float h  = an.w * expf(l.w * 0.2f);
    float x1 = cx - w * 0.5f;
    float y1 = cy - h * 0.5f;
    boxes[i] = make_float4(x1, y1, x1 + w, y1 + h);
}

// ---------------------------------------------------------------------------
// Kernel 1b: fused sigmoid + transpose (round-1 v4, passed).
// ---------------------------------------------------------------------------
__global__ __launch_bounds__(TNT) void sigT_kernel(const float* __restrict__ conf,
                                                   float* __restrict__ scoresT) {
    __shared__ float4 tile4[TILE_F4];          // 20.7 KB, linear (mirrors global)
    float* tile = (float*)tile4;

    const int a0 = blockIdx.x * TA;
    const int b  = blockIdx.y;
    const int t  = threadIdx.x;

    const float4* src = (const float4*)(conf + ((size_t)b * A_N + a0) * C_N);
#pragma unroll
    for (int i = 0; i < (TILE_F4 + TNT - 1) / TNT; ++i) {   // 6 iters (last partial)
        int idx4 = i * TNT + t;
        if (idx4 < TILE_F4) {
            float4 x = src[idx4];                            // dwordx4, coalesced
            float4 v;
            v.x = 1.0f / (1.0f + expf(-x.x));
            v.y = 1.0f / (1.0f + expf(-x.y));
            v.z = 1.0f / (1.0f + expf(-x.z));
            v.w = 1.0f / (1.0f + expf(-x.w));
            tile4[idx4] = v;                                 // ds_write_b128, dense
        }
    }
    __syncthreads();
    float* dst = scoresT + (size_t)b * C_N * A_N + a0;
#pragma unroll
    for (int i = 0; i < (TILE_F4 + TNT - 1) / TNT; ++i) {
        int idx4 = i * TNT + t;
        if (idx4 < TILE_F4) {
            int cc  = idx4 >> 4;                   // 16 float4 per class row
            int al4 = idx4 & 15;
            int e   = al4 * 4 * C_N + cc;
            float4 v;
            v.x = tile[e];
            v.y = tile[e + C_N];
            v.z = tile[e + 2 * C_N];
            v.w = tile[e + 3 * C_N];
            ((float4*)(dst + (size_t)cc * A_N))[al4] = v;   // dwordx4 stores
        }
    }
}

// ---------------------------------------------------------------------------
// Shared device routine: wave-level bitonic sort of <=CAP keys + box gather +
// ordered greedy NMS scan. Verbatim semantics from the passing rounds.
// ---------------------------------------------------------------------------
__device__ __forceinline__ void sort_gather_scan64(
        unsigned long long* cand, float4* cbox, int C, int lane,
        const float4* __restrict__ bptr, float* __restrict__ optr,
        float& rx1, float& ry1, float& rx2, float& ry2, float& rar,
        int& acc, int& kout) {
    unsigned long long key[8];
#pragma unroll
    for (int r = 0; r < 8; ++r) {
        int sidx = r * 64 + lane;
        key[r] = (sidx < C) ? cand[sidx] : 0ull;   // pad: 0 < any real key
    }
#pragma unroll
    for (int k = 2; k <= CAP; k <<= 1) {
#pragma unroll
        for (int j = k >> 1; j > 0; j >>= 1) {
            if (j >= 64) {
                int jr = j >> 6;               // 1,2,4: in-lane pairs
#pragma unroll
                for (int r = 0; r < 8; ++r) {
                    int rp = r ^ jr;
                    if (rp > r) {
                        int e = r * 64 + lane;
                        bool up = ((e & k) == 0);
                        unsigned long long va = key[r], vb = key[rp];
                        bool sw = up ? (va < vb) : (va > vb);
                        if (sw) { key[r] = vb; key[rp] = va; }
                    }
                }
            } else {                            // cross-lane via shfl
#pragma unroll
                for (int r = 0; r < 8; ++r) {
                    int e = r * 64 + lane;
                    bool up    = ((e & k) == 0);
                    bool isLow = ((lane & j) == 0);
                    unsigned long long va = key[r];
                    unsigned long long vb = __shfl_xor(va, j, 64);
                    bool keepMax = (up == isLow);
                    key[r] = keepMax ? (va > vb ? va : vb) : (va < vb ? va : vb);
                }
            }
        }
    }
    __syncthreads();
#pragma unroll
    for (int r = 0; r < 8; ++r) cand[r * 64 + lane] = key[r];
    __syncthreads();
#pragma unroll
    for (int r = 0; r < 8; ++r) {
        int e = r * 64 + lane;
        if (e < C) cbox[e] = bptr[(int)(~(unsigned)cand[e])];
    }
    __syncthreads();

    int ts = 0;
    unsigned long long k0 = cand[0];
    float4 cb = cbox[0];
    while (ts < C) {
        unsigned long long nk = 0ull;
        float4 nb = cb;
        if (ts + 1 < C) { nk = cand[ts + 1]; nb = cbox[ts + 1]; }
        float sc = __uint_as_float((unsigned)(k0 >> 32));
        float ca = (cb.z - cb.x) * (cb.w - cb.y);
        bool over = false;
        if (lane < acc) {
            float tlx = fmaxf(rx1, cb.x);
            float tly = fmaxf(ry1, cb.y);
            float brx = fminf(rx2, cb.z);
            float bry = fminf(ry2, cb.w);
            float iw  = fmaxf(brx - tlx, 0.0f);
            float ih  = fmaxf(bry - tly, 0.0f);
            float inter = iw * ih;
            float iou = inter / (rar + ca - inter);   // ref operand order
            over = iou > 0.5f;
        }
        if (!__any(over)) {
            if (lane == acc) { rx1 = cb.x; ry1 = cb.y; rx2 = cb.z; ry2 = cb.w; rar = ca; }
            if (lane == 0) {
                float* o = optr + (size_t)kout * 5;
                o[0] = sc; o[1] = cb.x; o[2] = cb.y; o[3] = cb.z; o[4] = cb.w;
            }
            acc++; kout++;
            if (acc == TOPK) break;
        }
        ++ts; k0 = nk; cb = nb;
    }
}

// ---------------------------------------------------------------------------
// Kernel 2a: STREAMING SELECT (split from round-0 fused kernel). 256 threads
// per (b,c): hist + band walk + band-0 compaction, written to workspace.
// All waves do parallel streaming work — no serial idle phase. Semantics of
// hist/bins/band-walk/clamp/keys identical to the passing rounds.
// ---------------------------------------------------------------------------
__global__ __launch_bounds__(SNT) void select_kernel(
        const float* __restrict__ scoresT,
        unsigned long long* __restrict__ g_cand,
        int* __restrict__ g_hist,
        int* __restrict__ g_cnt,
        int* __restrict__ g_blo) {
    __shared__ int hist[NBINS];
    __shared__ int s_cnt;

    const int bc = blockIdx.x;             // b*C_N + c
    const int t  = threadIdx.x;

    for (int i = t; i < NBINS; i += SNT) hist[i] = 0;
    if (t == 0) s_cnt = 0;
    __syncthreads();

    const float4* sptr = (const float4*)(scoresT + (size_t)bc * A_N);

    // --- pass 1: histogram (coalesced float4 reads, identical to round 0) ---
    for (int i = 0; i < A_N / 4 / SNT; ++i) {      // 16 iterations
        float4 s4 = sptr[t + SNT * i];
        float s[4] = {s4.x, s4.y, s4.z, s4.w};
#pragma unroll
        for (int q = 0; q < 4; ++q) {
            if (s[q] > 0.3f) {
                unsigned u = __float_as_uint(s[q]);
                int bin = (int)(u >> 16) - (int)BIN_BASE;
                bin = bin < 0 ? 0 : (bin > NBINS - 1 ? NBINS - 1 : bin);
                atomicAdd(&hist[bin], 1);
            }
        }
    }
    __syncthreads();

    // publish hist for kernel B's (rare) refill path
    for (int i = t; i < NBINS; i += SNT) g_hist[bc * NBINS + i] = hist[i];

    // --- band walk for band 0 (redundant on all threads, wave-uniform) ---
    int lo = NBINS, tot = 0;
    while (lo > 0) {
        int cnt = hist[lo - 1];
        if (tot + cnt > CAP) {
            if (tot == 0) { lo--; }                // single bin > CAP: take it (clamped)
            break;
        }
        tot += cnt; lo--;
    }
    const int bin_lo = lo;

    // --- pass 2: compact band 0 straight to workspace (L2-warm reads) ---
    if (bin_lo < NBINS) {
        for (int i = 0; i < A_N / 4 / SNT; ++i) {
            float4 s4 = sptr[t + SNT * i];
            float s[4] = {s4.x, s4.y, s4.z, s4.w};
#pragma unroll
            for (int q = 0; q < 4; ++q) {
                if (s[q] > 0.3f) {
                    unsigned u = __float_as_uint(s[q]);
                    int bin = (int)(u >> 16) - (int)BIN_BASE;
                    bin = bin < 0 ? 0 : (bin > NBINS - 1 ? NBINS - 1 : bin);
                    if (bin >= bin_lo && bin < NBINS) {
                        int slot = atomicAdd(&s_cnt, 1);
                        if (slot < CAP) {
                            unsigned a = (unsigned)(4 * (t + SNT * i) + q);
                            g_cand[(size_t)bc * CAP + slot] =
                                ((unsigned long long)u << 32) | (unsigned)(~a);
                        }
                    }
                }
            }
        }
    }
    __syncthreads();
    if (t == 0) {
        int C = s_cnt; if (C > CAP) C = CAP;
        g_cnt[bc] = C;
        g_blo[bc] = bin_lo;
    }
}

// ---------------------------------------------------------------------------
// Kernel 2b: SORT + GREEDY NMS. One 64-thread wave per (b,c); 13 KB LDS ->
// all 1296 blocks resident from t=0, serial chains overlap across blocks.
// Band 0 comes precompacted from kernel 2a; refill (rare: <64 accepts from
// 512 top candidates) continues the band walk reading scoresT directly —
// verbatim round-1 loop.
// ---------------------------------------------------------------------------
__global__ __launch_bounds__(64, 4) void nms_sorted_kernel(
        const float* __restrict__ scoresT,
        const float4* __restrict__ boxes,
        const unsigned long long* __restrict__ g_cand,
        const int* __restrict__ g_hist,
        const int* __restrict__ g_cnt,
        const int* __restrict__ g_blo,
        float* __restrict__ out) {
    __shared__ int hist[NBINS];
    __shared__ unsigned long long cand[CAP];
    __shared__ float4 cbox[CAP];
    __shared__ int s_cnt;

    const int bc   = blockIdx.x;
    const int b    = bc / C_N;
    const int lane = threadIdx.x;

    const float4* sptr = (const float4*)(scoresT + (size_t)bc * A_N);
    const float4* bptr = boxes + (size_t)b * A_N;
    float* optr = out + (size_t)bc * TOPK * 5;

    for (int i = lane; i < NBINS; i += 64) hist[i] = g_hist[bc * NBINS + i];
    const int C0 = g_cnt[bc];
    int bin_hi   = g_blo[bc];              // band 0 consumed bins [bin_hi, NBINS)
    for (int e = lane; e < C0; e += 64) cand[e] = g_cand[(size_t)bc * CAP + e];
    __syncthreads();

    float rx1 = 0.f, ry1 = 0.f, rx2 = 0.f, ry2 = 0.f, rar = 0.f;
    int acc = 0, kout = 0;

    if (C0 > 0)
        sort_gather_scan64(cand, cbox, C0, lane, bptr, optr,
                           rx1, ry1, rx2, ry2, rar, acc, kout);

    // --- refill loop (rare path; identical to round-1 fused kernel) ---
    while (acc < TOPK) {
        int lo = bin_hi, tot = 0;
        while (lo > 0) {
            int cnt = hist[lo - 1];
            if (tot + cnt > CAP) {
                if (tot == 0) { lo--; }
                break;
            }
            tot += cnt; lo--;
        }
        const int bin_lo = lo;
        if (bin_lo == bin_hi) break;               // exhausted
        if (lane == 0) s_cnt = 0;
        __syncthreads();

        for (int i = 0; i < A_N / 4 / 64; ++i) {
            float4 s4 = sptr[lane + 64 * i];
            float s[4] = {s4.x, s4.y, s4.z, s4.w};
#pragma unroll
            for (int q = 0; q < 4; ++q) {
                if (s[q] > 0.3f) {
                    unsigned u = __float_as_uint(s[q]);
                    int bin = (int)(u >> 16) - (int)BIN_BASE;
                    bin = bin < 0 ? 0 : (bin > NBINS - 1 ? NBINS - 1 : bin);
                    if (bin >= bin_lo && bin < bin_hi) {
                        int slot = atomicAdd(&s_cnt, 1);
                        if (slot < CAP) {
                            unsigned a = (unsigned)(4 * (lane + 64 * i) + q);
                            cand[slot] = ((unsigned long long)u << 32) | (unsigned)(~a);
                        }
                    }
                }
            }
        }
        __syncthreads();
        int C = s_cnt; if (C > CAP) C = CAP;
        if (C > 0)
            sort_gather_scan64(cand, cbox, C, lane, bptr, optr,
                               rx1, ry1, rx2, ry2, rar, acc, kout);
        bin_hi = bin_lo;
    }

    // Zero-fill remaining rows (harness poisons d_out with 0xAA every launch).
    {
        float* o  = optr + (size_t)kout * 5;
        int   rem = (TOPK - kout) * 5;
        for (int i = lane; i < rem; i += 64) o[i] = 0.0f;
    }
}

// ---------------------------------------------------------------------------
// Tier-2: round-0 fused select+NMS (proven 80 µs) if ws lacks split buffers.
// ---------------------------------------------------------------------------
__global__ __launch_bounds__(SNT, 4) void select_nms_fused(
        const float* __restrict__ scoresT,
        const float4* __restrict__ boxes,
        float* __restrict__ out) {
    __shared__ int hist[NBINS];
    __shared__ unsigned long long cand[CAP];
    __shared__ float4 cbox[CAP];
    __shared__ int s_cnt, s_acc, s_kout;

    const int bc   = blockIdx.x;
    const int b    = bc / C_N;
    const int t    = threadIdx.x;
    const int lane = t & 63;
    const int wv   = t >> 6;

    for (int i = t; i < NBINS; i += SNT) hist[i] = 0;
    if (t == 0) { s_acc = 0; s_kout = 0; }
    __syncthreads();

    const float4* sptr = (const float4*)(scoresT + (size_t)bc * A_N);
    const float4* bptr = boxes + (size_t)b * A_N;
    float* optr = out + (size_t)bc * TOPK * 5;

    for (int i = 0; i < A_N / 4 / SNT; ++i) {
        float4 s4 = sptr[t + SNT * i];
        float s[4] = {s4.x, s4.y, s4.z, s4.w};
#pragma unroll
        for (int q = 0; q < 4; ++q) {
            if (s[q] > 0.3f) {
                unsigned u = __float_as_uint(s[q]);
                int bin = (int)(u >> 16) - (int)BIN_BASE;
                bin = bin < 0 ? 0 : (bin > NBINS - 1 ? NBINS - 1 : bin);
                atomicAdd(&hist[bin], 1);
            }
        }
    }
    __syncthreads();

    float rx1 = 0.f, ry1 = 0.f, rx2 = 0.f, ry2 = 0.f, rar = 0.f;
    int acc = 0, kout = 0;

    int bin_hi = NBINS;
    for (;;) {
        int lo = bin_hi, tot = 0;
        while (lo > 0) {
            int cnt = hist[lo - 1];
            if (tot + cnt > CAP) { if (tot == 0) { lo--; } break; }
            tot += cnt; lo--;
        }
        const int bin_lo = lo;
        if (bin_lo == bin_hi) break;
        if (t == 0) s_cnt = 0;
        __syncthreads();

        for (int i = 0; i < A_N / 4 / SNT; ++i) {
            float4 s4 = sptr[t + SNT * i];
            float s[4] = {s4.x, s4.y, s4.z, s4.w};
#pragma unroll
            for (int q = 0; q < 4; ++q) {
                if (s[q] > 0.3f) {
                    unsigned u = __float_as_uint(s[q]);
                    int bin = (int)(u >> 16) - (int)BIN_BASE;
                    bin = bin < 0 ? 0 : (bin > NBINS - 1 ? NBINS - 1 : bin);
                    if (bin >= bin_lo && bin < bin_hi) {
                        int slot = atomicAdd(&s_cnt, 1);
                        if (slot < CAP) {
                            unsigned a = (unsigned)(4 * (t + SNT * i) + q);
                            cand[slot] = ((unsigned long long)u << 32) | (unsigned)(~a);
                        }
                    }
                }
            }
        }
        __syncthreads();
        int C = s_cnt; if (C > CAP) C = CAP;

        if (C > 0) {
            if (wv == 0) {
                unsigned long long key[8];
#pragma unroll
                for (int r = 0; r < 8; ++r) {
                    int sidx = r * 64 + lane;
                    key[r] = (sidx < C) ? cand[sidx] : 0ull;
                }
#pragma unroll
                for (int k = 2; k <= CAP; k <<= 1) {
#pragma unroll
                    for (int j = k >> 1; j > 0; j >>= 1) {
                        if (j >= 64) {
                            int jr = j >> 6;
#pragma unroll
                            for (int r = 0; r < 8; ++r) {
                                int rp = r ^ jr;
                                if (rp > r) {
                                    int e = r * 64 + lane;
                                    bool up = ((e & k) == 0);
                                    unsigned long long va = key[r], vb = key[rp];
                                    bool sw = up ? (va < vb) : (va > vb);
                                    if (sw) { key[r] = vb; key[rp] = va; }
                                }
                            }
                        } else {
#pragma unroll
                            for (int r = 0; r < 8; ++r) {
                                int e = r * 64 + lane;
                                bool up    = ((e & k) == 0);
                                bool isLow = ((lane & j) == 0);
                                unsigned long long va = key[r];
                                unsigned long long vb = __shfl_xor(va, j, 64);
                                bool keepMax = (up == isLow);
                                key[r] = keepMax ? (va > vb ? va : vb)
                                                 : (va < vb ? va : vb);
                            }
                        }
                    }
                }
#pragma unroll
                for (int r = 0; r < 8; ++r) cand[r * 64 + lane] = key[r];
            }
            __syncthreads();

            for (int e = t; e < CAP; e += SNT)
                if (e < C) cbox[e] = bptr[(int)(~(unsigned)cand[e])];
            __syncthreads();

            if (wv == 0) {
                int ts = 0;
                unsigned long long k0 = cand[0];
                float4 cb = cbox[0];
                while (ts < C) {
                    unsigned long long nk = 0ull;
                    float4 nb = cb;
                    if (ts + 1 < C) { nk = cand[ts + 1]; nb = cbox[ts + 1]; }
                    float sc = __uint_as_float((unsigned)(k0 >> 32));
                    float ca = (cb.z - cb.x) * (cb.w - cb.y);
                    bool over = false;
                    if (lane < acc) {
                        float tlx = fmaxf(rx1, cb.x);
                        float tly = fmaxf(ry1, cb.y);
                        float brx = fminf(rx2, cb.z);
                        float bry = fminf(ry2, cb.w);
                        float iw  = fmaxf(brx - tlx, 0.0f);
                        float ih  = fmaxf(bry - tly, 0.0f);
                        float inter = iw * ih;
                        float iou = inter / (rar + ca - inter);
                        over = iou > 0.5f;
                    }
                    if (!__any(over)) {
                        if (lane == acc) { rx1 = cb.x; ry1 = cb.y; rx2 = cb.z; ry2 = cb.w; rar = ca; }
                        if (lane == 0) {
                            float* o = optr + (size_t)kout * 5;
                            o[0] = sc; o[1] = cb.x; o[2] = cb.y; o[3] = cb.z; o[4] = cb.w;
                        }
                        acc++; kout++;
                        if (acc == TOPK) break;
                    }
                    ++ts; k0 = nk; cb = nb;
                }
                if (lane == 0) { s_acc = acc; s_kout = kout; }
            }
            __syncthreads();
            if (s_acc >= TOPK) break;
        }
        bin_hi = bin_lo;
    }

    {
        const int ko = s_kout;
        float* o  = optr + (size_t)ko * 5;
        int   rem = (TOPK - ko) * 5;
        for (int i = t; i < rem; i += SNT) o[i] = 0.0f;
    }
}

// ---------------------------------------------------------------------------
// Tier-3 fallback: standalone one-wave NMS reading strided conf (r6-8 path).
// ---------------------------------------------------------------------------
__global__ __launch_bounds__(64, 4) void nms_fallback(const float* __restrict__ conf,
                                                      const float4* __restrict__ boxes,
                                                      float* __restrict__ out) {
    __shared__ int hist[NBINS];
    __shared__ unsigned long long cand[CAP];
    __shared__ float4 cbox[CAP];
    __shared__ int s_cnt;

    const int c    = blockIdx.x;
    const int b    = blockIdx.y;
    const int lane = threadIdx.x;

    const float4* bptr = boxes + (size_t)b * A_N;
    const float*  cptr = conf + (size_t)b * A_N * C_N + c;
    float* optr = out + (size_t)(b * C_N + c) * TOPK * 5;

    for (int i = lane; i < NBINS; i += 64) hist[i] = 0;
    __syncthreads();
    for (int i = 0; i < A_N / 256; ++i) {
        int a0 = 4 * (lane + 64 * i);
#pragma unroll
        for (int q = 0; q < 4; ++q) {
            float x = cptr[(size_t)(a0 + q) * C_N];
            float s = 1.0f / (1.0f + expf(-x));
            if (s > 0.3f) {
                unsigned u = __float_as_uint(s);
                int bin = (int)(u >> 16) - (int)BIN_BASE;
                bin = bin < 0 ? 0 : (bin > NBINS - 1 ? NBINS - 1 : bin);
                atomicAdd(&hist[bin], 1);
            }
        }
    }
    __syncthreads();

    float rx1 = 0.f, ry1 = 0.f, rx2 = 0.f, ry2 = 0.f, rar = 0.f;
    int acc = 0, kout = 0;
    int bin_hi = NBINS;
    for (;;) {
        int lo = bin_hi, tot = 0;
        while (lo > 0) {
            int cnt = hist[lo - 1];
            if (tot + cnt > CAP) { if (tot == 0) { lo--; } break; }
            tot += cnt; lo--;
        }
        const int bin_lo = lo;
        if (bin_lo == bin_hi) break;
        if (lane == 0) s_cnt = 0;
        __syncthreads();
        for (int i = 0; i < A_N / 256; ++i) {
            int a0 = 4 * (lane + 64 * i);
#pragma unroll
            for (int q = 0; q < 4; ++q) {
                float x = cptr[(size_t)(a0 + q) * C_N];
                float s = 1.0f / (1.0f + expf(-x));
                if (s > 0.3f) {
                    unsigned u = __float_as_uint(s);
                    int bin = (int)(u >> 16) - (int)BIN_BASE;
                    bin = bin < 0 ? 0 : (bin > NBINS - 1 ? NBINS - 1 : bin);
                    if (bin >= bin_lo && bin < bin_hi) {
                        int slot = atomicAdd(&s_cnt, 1);
                        if (slot < CAP)
                            cand[slot] = ((unsigned long long)u << 32) | (unsigned)(~(unsigned)(a0 + q));
                    }
                }
            }
        }
        __syncthreads();
        int C = s_cnt; if (C > CAP) C = CAP;
        if (C > 0)
            sort_gather_scan64(cand, cbox, C, lane, bptr, optr,
                               rx1, ry1, rx2, ry2, rar, acc, kout);
        if (acc == TOPK) break;
        bin_hi = bin_lo;
    }
    {
        float* o  = optr + (size_t)kout * 5;
        int   rem = (TOPK - kout) * 5;
        for (int i = lane; i < rem; i += 64) o[i] = 0.0f;
    }
}

extern "C" void kernel_launch(void* const* d_in, const int* in_sizes, int n_in,
                              void* d_out, int out_size, void* d_ws, size_t ws_size,
                              hipStream_t stream) {
    const float* loc     = (const float*)d_in[0];   // [B, A, 4]
    const float* conf    = (const float*)d_in[1];   // [B, A, C]
    const float* anchors = (const float*)d_in[2];   // [A, 4]
    float* out = (float*)d_out;                     // [B, C, TOPK, 5]

    const size_t boxes_bytes  = (size_t)B_N * A_N * sizeof(float4);          // 4 MB
    const size_t scores_bytes = (size_t)B_N * C_N * A_N * sizeof(float);     // 85 MB
    const size_t cand_bytes   = (size_t)BC_N * CAP * sizeof(unsigned long long); // 5.3 MB
    const size_t hist_bytes   = (size_t)BC_N * NBINS * sizeof(int);          // 1.2 MB
    const size_t cnt_bytes    = (size_t)BC_N * sizeof(int);
    const size_t full_bytes   = boxes_bytes + scores_bytes + cand_bytes +
                                hist_bytes + 2 * cnt_bytes;                  // ~95.7 MB

    float4* boxes = (float4*)d_ws;

    decode_kernel<<<(B_N * A_N) / DNT, DNT, 0, stream>>>(
        (const float4*)loc, (const float4*)anchors, boxes);

    if (ws_size >= full_bytes) {
        char* p = (char*)d_ws + boxes_bytes;
        float* scoresT = (float*)p;                 p += scores_bytes;
        unsigned long long* g_cand = (unsigned long long*)p; p += cand_bytes;
        int* g_hist = (int*)p;                      p += hist_bytes;
        int* g_cnt  = (int*)p;                      p += cnt_bytes;
        int* g_blo  = (int*)p;

        sigT_kernel<<<dim3(A_N / TA, B_N), TNT, 0, stream>>>(conf, scoresT);
        select_kernel<<<dim3(BC_N), SNT, 0, stream>>>(scoresT, g_cand, g_hist, g_cnt, g_blo);
        nms_sorted_kernel<<<dim3(BC_N), 64, 0, stream>>>(scoresT, boxes, g_cand,
                                                         g_hist, g_cnt, g_blo, out);
    } else if (ws_size >= boxes_bytes + scores_bytes) {
        float* scoresT = (float*)((char*)d_ws + boxes_bytes);
        sigT_kernel<<<dim3(A_N / TA, B_N), TNT, 0, stream>>>(conf, scoresT);
        select_nms_fused<<<dim3(BC_N), SNT, 0, stream>>>(scoresT, boxes, out);
    } else {
        nms_fallback<<<dim3(C_N, B_N), 64, 0, stream>>>(conf, boxes, out);
    }
}